// Round 7
// baseline (124.450 us; speedup 1.0000x reference)
//
#include <hip/hip_runtime.h>
#include <math.h>

// Segmented sum over n rows into `batch` (<=8192) segments + log-sigmoid epilogue.
// out[2*b+0] = log(sigmoid(10*(1 - sum(l1+l2))) + 1e-10)
// out[2*b+1] = log(sigmoid(10*(5 - sum(l0)))    + 1e-10)
//
// R5/R6 finding: LDS atomic pipe processes ~1 lane-4B-op/1.2cyc/CU; time is
// conserved in atomic BYTES (u64 == 2xu32). At 8B/row the LDS-only floor is
// ~33us. R7: hybrid — 3/4 of row-groups use LDS ds_add_u64; 1/4 use native
// global u64 atomics (TCC pipe, runs concurrently) into a 64-replica table.
// Packed format per segment slot: [63:37]=q1 | [36:10]=q0 | [9:0]=count,
// per add q = rn(v*2^17 + 2^21), reducer recovers sum = qsum - K*2^21.

constexpr float KSHARP = 10.0f;
constexpr float EPS    = 1e-10f;
constexpr int   SEG    = 8192;
constexpr int   S2     = 2 * SEG;
constexpr int   NREP   = 64;                  // global-table replica slabs

constexpr float SCALE     = 131072.0f;        // 2^17
constexpr float INV_SCALE = 1.0f / 131072.0f;
constexpr float MAGIC     = 2097152.0f + 8388608.0f;  // bias 2^21 + 2^23 cvt magic
constexpr long long BIAS_I = 2097152;         // 2^21 per-add bias in fixed units

__device__ __forceinline__ unsigned fix22(float v) {
    // round-to-nearest (v*2^17 + 2^21) for v in (-16,48) via 2^23 magic constant
    float f = __builtin_fmaf(v, SCALE, MAGIC);
    return __float_as_uint(f) & 0x3FFFFFu;
}

__device__ __forceinline__ unsigned long long pack_row(float v1, float v0) {
    return ((unsigned long long)fix22(v1) << 37)
         | ((unsigned long long)fix22(v0) << 10) | 1ull;
}

__global__ __launch_bounds__(1024, 8) void seg_hybrid_kernel(
    const float* __restrict__ logits, const int* __restrict__ idx,
    unsigned long long* __restrict__ partials,   // nb slabs of SEG u64
    unsigned long long* __restrict__ gtab,       // NREP slabs, pre-zeroed
    int n, int chunk)
{
    __shared__ unsigned long long acc[SEG];      // 64 KiB
    for (int i = threadIdx.x; i < SEG; i += blockDim.x) acc[i] = 0ull;
    __syncthreads();

    int cs = blockIdx.x * chunk;
    int ce = cs + chunk; if (ce > n) ce = n;
    if (cs < ce) {
        int rows = ce - cs;
        int ngr  = rows >> 2;
        for (int g = threadIdx.x; g < ngr; g += blockDim.x) {
            int r = cs + (g << 2);
            const float4* p = (const float4*)(logits + 3 * (size_t)r);
            float4 a = p[0], b = p[1], c = p[2];
            int4 id = *(const int4*)(idx + r);
            // row0: a.x a.y a.z | row1: a.w b.x b.y | row2: b.z b.w c.x | row3: c.y c.z c.w
            unsigned long long w0 = pack_row(a.y + a.z, a.x);
            unsigned long long w1 = pack_row(b.x + b.y, a.w);
            unsigned long long w2 = pack_row(b.w + c.x, b.z);
            unsigned long long w3 = pack_row(c.z + c.w, c.y);
            if ((g & 3) == 3) {
                // global path: replicated table, TCC atomic pipe
                unsigned long long* t =
                    gtab + (size_t)(((g >> 2) + blockIdx.x) & (NREP - 1)) * SEG;
                atomicAdd(&t[id.x], w0);
                atomicAdd(&t[id.y], w1);
                atomicAdd(&t[id.z], w2);
                atomicAdd(&t[id.w], w3);
            } else {
                // LDS path
                atomicAdd(&acc[id.x], w0);
                atomicAdd(&acc[id.y], w1);
                atomicAdd(&acc[id.z], w2);
                atomicAdd(&acc[id.w], w3);
            }
        }
        int tail = rows & 3;
        if ((int)threadIdx.x < tail) {
            int r = cs + (ngr << 2) + threadIdx.x;
            float l0 = logits[3 * (size_t)r], l1 = logits[3 * (size_t)r + 1],
                  l2 = logits[3 * (size_t)r + 2];
            atomicAdd(&acc[idx[r]], pack_row(l1 + l2, l0));
        }
    }
    __syncthreads();
    int4* dst = (int4*)(partials + (size_t)blockIdx.x * SEG);
    const int4* src = (const int4*)acc;
    for (int i = threadIdx.x; i < SEG / 2; i += blockDim.x) dst[i] = src[i];
}

__global__ __launch_bounds__(1024) void reduce_pack_kernel(
    const unsigned long long* __restrict__ slabs, float* __restrict__ out,
    int nslabs, int batch)
{
    // blockDim (64,16); each thread owns 2 consecutive u64 columns (16B loads)
    int col2 = blockIdx.x * 64 + threadIdx.x;
    long long s1a = 0, s0a = 0, s1b = 0, s0b = 0;
    for (int b = threadIdx.y; b < nslabs; b += 16) {
        const unsigned long long* row = slabs + (size_t)b * SEG + 2 * col2;
        unsigned long long u0 = row[0];
        unsigned long long u1 = row[1];
        long long K0 = (long long)(u0 & 0x3FFull);
        long long K1 = (long long)(u1 & 0x3FFull);
        s0a += (long long)((u0 >> 10) & 0x7FFFFFFull) - K0 * BIAS_I;
        s1a += (long long)(u0 >> 37)                  - K0 * BIAS_I;
        s0b += (long long)((u1 >> 10) & 0x7FFFFFFull) - K1 * BIAS_I;
        s1b += (long long)(u1 >> 37)                  - K1 * BIAS_I;
    }
    __shared__ long long red[16][64][4];
    red[threadIdx.y][threadIdx.x][0] = s1a;
    red[threadIdx.y][threadIdx.x][1] = s0a;
    red[threadIdx.y][threadIdx.x][2] = s1b;
    red[threadIdx.y][threadIdx.x][3] = s0b;
    __syncthreads();
    if (threadIdx.y == 0) {
        long long t[4] = {0, 0, 0, 0};
        #pragma unroll
        for (int y = 0; y < 16; ++y) {
            t[0] += red[y][threadIdx.x][0];
            t[1] += red[y][threadIdx.x][1];
            t[2] += red[y][threadIdx.x][2];
            t[3] += red[y][threadIdx.x][3];
        }
        #pragma unroll
        for (int q = 0; q < 2; ++q) {
            int j = 2 * col2 + q;
            if (j < batch) {
                float s1 = (float)t[2 * q]     * INV_SCALE;
                float s0 = (float)t[2 * q + 1] * INV_SCALE;
                float x1 = KSHARP * (1.0f - s1);
                float x0 = KSHARP * (5.0f - s0);
                float sg1, sg0;
                if (x1 >= 0.0f) { sg1 = 1.0f / (1.0f + expf(-x1)); }
                else            { float e = expf(x1); sg1 = e / (1.0f + e); }
                if (x0 >= 0.0f) { sg0 = 1.0f / (1.0f + expf(-x0)); }
                else            { float e = expf(x0); sg0 = e / (1.0f + e); }
                out[2 * j + 0] = logf(sg1 + EPS);
                out[2 * j + 1] = logf(sg0 + EPS);
            }
        }
    }
}

// ---- secondary path (chunk too large for packed count fields): u32 fixed-point ----
constexpr float SCALE21     = 2097152.0f;
constexpr float INV_SCALE21 = 1.0f / 2097152.0f;

__global__ __launch_bounds__(1024, 8) void seg_partial_kernel(
    const float* __restrict__ logits, const int* __restrict__ idx,
    int* __restrict__ partials, int n, int chunk)
{
    __shared__ int s1[SEG];
    __shared__ int s0[SEG];
    {
        int4 z = make_int4(0, 0, 0, 0);
        int4* p1 = (int4*)s1; int4* p0 = (int4*)s0;
        for (int i = threadIdx.x; i < SEG / 4; i += blockDim.x) { p1[i] = z; p0[i] = z; }
    }
    __syncthreads();
    long long cs = (long long)blockIdx.x * chunk;
    long long ce = cs + chunk; if (ce > n) ce = n;
    if (cs < ce) {
        int rows = (int)(ce - cs);
        int ngr  = rows >> 2;
        for (int g = threadIdx.x; g < ngr; g += blockDim.x) {
            long long r = cs + ((long long)g << 2);
            const float4* p = (const float4*)(logits + 3 * r);
            float4 a = p[0], b = p[1], c = p[2];
            int4 id = *(const int4*)(idx + r);
            atomicAdd(&s1[id.x], __float2int_rn((a.y + a.z) * SCALE21));
            atomicAdd(&s0[id.x], __float2int_rn(a.x * SCALE21));
            atomicAdd(&s1[id.y], __float2int_rn((b.x + b.y) * SCALE21));
            atomicAdd(&s0[id.y], __float2int_rn(a.w * SCALE21));
            atomicAdd(&s1[id.z], __float2int_rn((b.w + c.x) * SCALE21));
            atomicAdd(&s0[id.z], __float2int_rn(b.z * SCALE21));
            atomicAdd(&s1[id.w], __float2int_rn((c.z + c.w) * SCALE21));
            atomicAdd(&s0[id.w], __float2int_rn(c.y * SCALE21));
        }
        int tail = rows & 3;
        if ((int)threadIdx.x < tail) {
            long long r = cs + ((long long)ngr << 2) + threadIdx.x;
            float l0 = logits[3 * r], l1 = logits[3 * r + 1], l2 = logits[3 * r + 2];
            int b = idx[r];
            atomicAdd(&s1[b], __float2int_rn((l1 + l2) * SCALE21));
            atomicAdd(&s0[b], __float2int_rn(l0 * SCALE21));
        }
    }
    __syncthreads();
    int4* dst = (int4*)(partials + (size_t)blockIdx.x * S2);
    const int4* p1 = (const int4*)s1;
    const int4* p0 = (const int4*)s0;
    for (int i = threadIdx.x; i < SEG / 4; i += blockDim.x) dst[i] = p1[i];
    for (int i = threadIdx.x; i < SEG / 4; i += blockDim.x) dst[SEG / 4 + i] = p0[i];
}

__global__ __launch_bounds__(1024) void reduce_finalize_kernel(
    const int* __restrict__ partials, float* __restrict__ out,
    int nb, int batch)
{
    int col4 = blockIdx.x * 64 + threadIdx.x;
    const int4* p4 = (const int4*)partials;
    long long a0 = 0, a1 = 0, a2 = 0, a3 = 0;
    for (int b = threadIdx.y; b < nb; b += 16) {
        int4 v = p4[(size_t)b * (S2 / 4) + col4];
        a0 += v.x; a1 += v.y; a2 += v.z; a3 += v.w;
    }
    __shared__ long long red[16][64][4];
    red[threadIdx.y][threadIdx.x][0] = a0;
    red[threadIdx.y][threadIdx.x][1] = a1;
    red[threadIdx.y][threadIdx.x][2] = a2;
    red[threadIdx.y][threadIdx.x][3] = a3;
    __syncthreads();
    if (threadIdx.y == 0) {
        long long t[4] = {0, 0, 0, 0};
        #pragma unroll
        for (int y = 0; y < 16; ++y) {
            t[0] += red[y][threadIdx.x][0];
            t[1] += red[y][threadIdx.x][1];
            t[2] += red[y][threadIdx.x][2];
            t[3] += red[y][threadIdx.x][3];
        }
        #pragma unroll
        for (int q = 0; q < 4; ++q) {
            int j = col4 * 4 + q;
            float s = (float)t[q] * INV_SCALE21;
            bool is_s1 = (j < SEG);
            int  b     = is_s1 ? j : j - SEG;
            if (b < batch) {
                float C = is_s1 ? 1.0f : 5.0f;
                float x = KSHARP * (C - s);
                float sig;
                if (x >= 0.0f) { sig = 1.0f / (1.0f + expf(-x)); }
                else           { float e = expf(x); sig = e / (1.0f + e); }
                out[2 * b + (is_s1 ? 0 : 1)] = logf(sig + EPS);
            }
        }
    }
}

// ---- tertiary fallback (tiny ws or batch > 8192): global float atomics ----
__global__ void accum_atomic_kernel(const float* __restrict__ logits,
                                    const int* __restrict__ idx,
                                    float* __restrict__ sums, int n)
{
    int tid = blockIdx.x * blockDim.x + threadIdx.x;
    int stride = gridDim.x * blockDim.x;
    for (long long r = tid; r < n; r += stride) {
        float l0 = logits[3 * r], l1 = logits[3 * r + 1], l2 = logits[3 * r + 2];
        int b = idx[r];
        atomicAdd(&sums[2 * b],     l1 + l2);
        atomicAdd(&sums[2 * b + 1], l0);
    }
}

__global__ void finalize_kernel(const float* __restrict__ sums,
                                float* __restrict__ out, int total)
{
    int j = blockIdx.x * blockDim.x + threadIdx.x;
    if (j >= total) return;
    float s = sums[j];
    float C = (j & 1) ? 5.0f : 1.0f;
    float x = KSHARP * (C - s);
    float sig;
    if (x >= 0.0f) { sig = 1.0f / (1.0f + expf(-x)); }
    else           { float e = expf(x); sig = e / (1.0f + e); }
    out[j] = logf(sig + EPS);
}

extern "C" void kernel_launch(void* const* d_in, const int* in_sizes, int n_in,
                              void* d_out, int out_size, void* d_ws, size_t ws_size,
                              hipStream_t stream) {
    const float* logits = (const float*)d_in[0];
    const int*   idx    = (const int*)d_in[1];
    int n     = in_sizes[1];       // rows (8388608)
    int batch = out_size / 2;      // 8192
    float* out = (float*)d_out;

    const size_t SLAB = (size_t)SEG * 8;          // 64 KiB
    int slabs_total = (int)(ws_size / SLAB);

    if (batch <= SEG && slabs_total >= 8 + NREP) {
        int nb = slabs_total - NREP; if (nb > 512) nb = 512;
        long long chunk_ll = ((long long)n + nb - 1) / nb;
        int chunk = (int)((chunk_ll + 3) & ~3LL);
        if (chunk <= 8 * batch) {
            // primary: hybrid LDS + global-atomic path
            unsigned long long* partials = (unsigned long long*)d_ws;
            unsigned long long* gtab     = partials + (size_t)nb * SEG;
            hipMemsetAsync(gtab, 0, (size_t)NREP * SLAB, stream);
            seg_hybrid_kernel<<<nb, 1024, 0, stream>>>(logits, idx, partials, gtab, n, chunk);
            dim3 rb(64, 16);
            reduce_pack_kernel<<<SEG / 128, rb, 0, stream>>>(partials, out, nb + NREP, batch);
        } else {
            // secondary: u32 path (2 LDS atomics per row)
            int* partials = (int*)d_ws;
            int nb2 = slabs_total; if (nb2 > 512) nb2 = 512;
            long long c2 = ((long long)n + nb2 - 1) / nb2;
            int chunk2 = (int)((c2 + 3) & ~3LL);
            seg_partial_kernel<<<nb2, 1024, 0, stream>>>(logits, idx, partials, n, chunk2);
            dim3 rb(64, 16);
            reduce_finalize_kernel<<<S2 / 256, rb, 0, stream>>>(partials, out, nb2, batch);
        }
    } else {
        float* sums = (float*)d_ws;
        hipMemsetAsync(sums, 0, (size_t)2 * batch * sizeof(float), stream);
        int threads = 256;
        int blocks = (n + threads - 1) / threads;
        if (blocks > 2048) blocks = 2048;
        accum_atomic_kernel<<<blocks, threads, 0, stream>>>(logits, idx, sums, n);
        int total = 2 * batch;
        finalize_kernel<<<(total + 255) / 256, 256, 0, stream>>>(sums, out, total);
    }
}

// Round 8
// 35.869 us; speedup vs baseline: 3.4696x; 3.4696x over previous
//
#include <hip/hip_runtime.h>
#include <math.h>

// Segmented sum over n rows into `batch` (<=8192) segments + log-sigmoid epilogue.
// out[2*b+0] = log(sigmoid(10*(1 - sum(l1+l2))) + 1e-10)
// out[2*b+1] = log(sigmoid(10*(5 - sum(l0)))    + 1e-10)
//
// Model (R3/R5/R6/R7 evidence): LDS atomic unit is byte-rate-limited
// (~2.9 B/cyc/CU; u64 == 2xu32 in time; float atomicAdd CAS-expands 2.4x
// slower; global atomics write through to HBM-side, ~22ns each). Precision
// floor requires >=27-bit fixed-point fields -> 8 B/row atomic traffic is
// minimal. This version: pure-LDS packed u64 path, nb=256 blocks (1/CU) to
// halve the partials round-trip.
// Packed format per segment slot: [63:37]=q1 | [36:10]=q0 | [9:0]=count,
// per add q = rn(v*2^17 + 2^21); reducer recovers sum = qsum - K*2^21.

constexpr float KSHARP = 10.0f;
constexpr float EPS    = 1e-10f;
constexpr int   SEG    = 8192;
constexpr int   S2     = 2 * SEG;

constexpr float SCALE     = 131072.0f;        // 2^17
constexpr float INV_SCALE = 1.0f / 131072.0f;
constexpr float MAGIC     = 2097152.0f + 8388608.0f;  // bias 2^21 + 2^23 cvt magic
constexpr long long BIAS_I = 2097152;         // 2^21 per-add bias in fixed units

__device__ __forceinline__ unsigned fix22(float v) {
    // round-to-nearest (v*2^17 + 2^21) for |v|<16 via 2^23 magic constant
    float f = __builtin_fmaf(v, SCALE, MAGIC);
    return __float_as_uint(f) & 0x3FFFFFu;
}

__device__ __forceinline__ unsigned long long pack_row(float v1, float v0) {
    return ((unsigned long long)fix22(v1) << 37)
         | ((unsigned long long)fix22(v0) << 10) | 1ull;
}

__global__ __launch_bounds__(1024, 8) void seg_pack_kernel(
    const float* __restrict__ logits, const int* __restrict__ idx,
    unsigned long long* __restrict__ partials, int n, int chunk)
{
    __shared__ unsigned long long acc[SEG];   // 64 KiB
    for (int i = threadIdx.x; i < SEG; i += blockDim.x) acc[i] = 0ull;
    __syncthreads();

    int cs = blockIdx.x * chunk;
    int ce = cs + chunk; if (ce > n) ce = n;
    if (cs < ce) {
        int rows = ce - cs;
        int ngr  = rows >> 2;
        for (int g = threadIdx.x; g < ngr; g += blockDim.x) {
            int r = cs + (g << 2);
            const float4* p = (const float4*)(logits + 3 * (size_t)r);
            float4 a = p[0], b = p[1], c = p[2];
            int4 id = *(const int4*)(idx + r);
            // row0: a.x a.y a.z | row1: a.w b.x b.y | row2: b.z b.w c.x | row3: c.y c.z c.w
            atomicAdd(&acc[id.x], pack_row(a.y + a.z, a.x));
            atomicAdd(&acc[id.y], pack_row(b.x + b.y, a.w));
            atomicAdd(&acc[id.z], pack_row(b.w + c.x, b.z));
            atomicAdd(&acc[id.w], pack_row(c.z + c.w, c.y));
        }
        int tail = rows & 3;
        if ((int)threadIdx.x < tail) {
            int r = cs + (ngr << 2) + threadIdx.x;
            float l0 = logits[3 * (size_t)r], l1 = logits[3 * (size_t)r + 1],
                  l2 = logits[3 * (size_t)r + 2];
            atomicAdd(&acc[idx[r]], pack_row(l1 + l2, l0));
        }
    }
    __syncthreads();
    int4* dst = (int4*)(partials + (size_t)blockIdx.x * SEG);
    const int4* src = (const int4*)acc;
    for (int i = threadIdx.x; i < SEG / 2; i += blockDim.x) dst[i] = src[i];
}

__global__ __launch_bounds__(1024) void reduce_pack_kernel(
    const unsigned long long* __restrict__ slabs, float* __restrict__ out,
    int nslabs, int batch)
{
    // blockDim (64,16); each thread owns 2 consecutive u64 columns (16B loads)
    int col2 = blockIdx.x * 64 + threadIdx.x;
    long long s1a = 0, s0a = 0, s1b = 0, s0b = 0;
    for (int b = threadIdx.y; b < nslabs; b += 16) {
        const unsigned long long* row = slabs + (size_t)b * SEG + 2 * col2;
        unsigned long long u0 = row[0];
        unsigned long long u1 = row[1];
        long long K0 = (long long)(u0 & 0x3FFull);
        long long K1 = (long long)(u1 & 0x3FFull);
        s0a += (long long)((u0 >> 10) & 0x7FFFFFFull) - K0 * BIAS_I;
        s1a += (long long)(u0 >> 37)                  - K0 * BIAS_I;
        s0b += (long long)((u1 >> 10) & 0x7FFFFFFull) - K1 * BIAS_I;
        s1b += (long long)(u1 >> 37)                  - K1 * BIAS_I;
    }
    __shared__ long long red[16][64][4];
    red[threadIdx.y][threadIdx.x][0] = s1a;
    red[threadIdx.y][threadIdx.x][1] = s0a;
    red[threadIdx.y][threadIdx.x][2] = s1b;
    red[threadIdx.y][threadIdx.x][3] = s0b;
    __syncthreads();
    if (threadIdx.y == 0) {
        long long t[4] = {0, 0, 0, 0};
        #pragma unroll
        for (int y = 0; y < 16; ++y) {
            t[0] += red[y][threadIdx.x][0];
            t[1] += red[y][threadIdx.x][1];
            t[2] += red[y][threadIdx.x][2];
            t[3] += red[y][threadIdx.x][3];
        }
        #pragma unroll
        for (int q = 0; q < 2; ++q) {
            int j = 2 * col2 + q;
            if (j < batch) {
                float s1 = (float)t[2 * q]     * INV_SCALE;
                float s0 = (float)t[2 * q + 1] * INV_SCALE;
                float x1 = KSHARP * (1.0f - s1);
                float x0 = KSHARP * (5.0f - s0);
                float sg1, sg0;
                if (x1 >= 0.0f) { sg1 = 1.0f / (1.0f + expf(-x1)); }
                else            { float e = expf(x1); sg1 = e / (1.0f + e); }
                if (x0 >= 0.0f) { sg0 = 1.0f / (1.0f + expf(-x0)); }
                else            { float e = expf(x0); sg0 = e / (1.0f + e); }
                out[2 * j + 0] = logf(sg1 + EPS);
                out[2 * j + 1] = logf(sg0 + EPS);
            }
        }
    }
}

// ---- secondary path (chunk too large for packed count fields): u32 fixed-point ----
constexpr float SCALE21     = 2097152.0f;
constexpr float INV_SCALE21 = 1.0f / 2097152.0f;

__global__ __launch_bounds__(1024, 8) void seg_partial_kernel(
    const float* __restrict__ logits, const int* __restrict__ idx,
    int* __restrict__ partials, int n, int chunk)
{
    __shared__ int s1[SEG];
    __shared__ int s0[SEG];
    {
        int4 z = make_int4(0, 0, 0, 0);
        int4* p1 = (int4*)s1; int4* p0 = (int4*)s0;
        for (int i = threadIdx.x; i < SEG / 4; i += blockDim.x) { p1[i] = z; p0[i] = z; }
    }
    __syncthreads();
    long long cs = (long long)blockIdx.x * chunk;
    long long ce = cs + chunk; if (ce > n) ce = n;
    if (cs < ce) {
        int rows = (int)(ce - cs);
        int ngr  = rows >> 2;
        for (int g = threadIdx.x; g < ngr; g += blockDim.x) {
            long long r = cs + ((long long)g << 2);
            const float4* p = (const float4*)(logits + 3 * r);
            float4 a = p[0], b = p[1], c = p[2];
            int4 id = *(const int4*)(idx + r);
            atomicAdd(&s1[id.x], __float2int_rn((a.y + a.z) * SCALE21));
            atomicAdd(&s0[id.x], __float2int_rn(a.x * SCALE21));
            atomicAdd(&s1[id.y], __float2int_rn((b.x + b.y) * SCALE21));
            atomicAdd(&s0[id.y], __float2int_rn(a.w * SCALE21));
            atomicAdd(&s1[id.z], __float2int_rn((b.w + c.x) * SCALE21));
            atomicAdd(&s0[id.z], __float2int_rn(b.z * SCALE21));
            atomicAdd(&s1[id.w], __float2int_rn((c.z + c.w) * SCALE21));
            atomicAdd(&s0[id.w], __float2int_rn(c.y * SCALE21));
        }
        int tail = rows & 3;
        if ((int)threadIdx.x < tail) {
            long long r = cs + ((long long)ngr << 2) + threadIdx.x;
            float l0 = logits[3 * r], l1 = logits[3 * r + 1], l2 = logits[3 * r + 2];
            int b = idx[r];
            atomicAdd(&s1[b], __float2int_rn((l1 + l2) * SCALE21));
            atomicAdd(&s0[b], __float2int_rn(l0 * SCALE21));
        }
    }
    __syncthreads();
    int4* dst = (int4*)(partials + (size_t)blockIdx.x * S2);
    const int4* p1 = (const int4*)s1;
    const int4* p0 = (const int4*)s0;
    for (int i = threadIdx.x; i < SEG / 4; i += blockDim.x) dst[i] = p1[i];
    for (int i = threadIdx.x; i < SEG / 4; i += blockDim.x) dst[SEG / 4 + i] = p0[i];
}

__global__ __launch_bounds__(1024) void reduce_finalize_kernel(
    const int* __restrict__ partials, float* __restrict__ out,
    int nb, int batch)
{
    int col4 = blockIdx.x * 64 + threadIdx.x;
    const int4* p4 = (const int4*)partials;
    long long a0 = 0, a1 = 0, a2 = 0, a3 = 0;
    for (int b = threadIdx.y; b < nb; b += 16) {
        int4 v = p4[(size_t)b * (S2 / 4) + col4];
        a0 += v.x; a1 += v.y; a2 += v.z; a3 += v.w;
    }
    __shared__ long long red[16][64][4];
    red[threadIdx.y][threadIdx.x][0] = a0;
    red[threadIdx.y][threadIdx.x][1] = a1;
    red[threadIdx.y][threadIdx.x][2] = a2;
    red[threadIdx.y][threadIdx.x][3] = a3;
    __syncthreads();
    if (threadIdx.y == 0) {
        long long t[4] = {0, 0, 0, 0};
        #pragma unroll
        for (int y = 0; y < 16; ++y) {
            t[0] += red[y][threadIdx.x][0];
            t[1] += red[y][threadIdx.x][1];
            t[2] += red[y][threadIdx.x][2];
            t[3] += red[y][threadIdx.x][3];
        }
        #pragma unroll
        for (int q = 0; q < 4; ++q) {
            int j = col4 * 4 + q;
            float s = (float)t[q] * INV_SCALE21;
            bool is_s1 = (j < SEG);
            int  b     = is_s1 ? j : j - SEG;
            if (b < batch) {
                float C = is_s1 ? 1.0f : 5.0f;
                float x = KSHARP * (C - s);
                float sig;
                if (x >= 0.0f) { sig = 1.0f / (1.0f + expf(-x)); }
                else           { float e = expf(x); sig = e / (1.0f + e); }
                out[2 * b + (is_s1 ? 0 : 1)] = logf(sig + EPS);
            }
        }
    }
}

// ---- tertiary fallback (tiny ws or batch > 8192): global float atomics ----
__global__ void accum_atomic_kernel(const float* __restrict__ logits,
                                    const int* __restrict__ idx,
                                    float* __restrict__ sums, int n)
{
    int tid = blockIdx.x * blockDim.x + threadIdx.x;
    int stride = gridDim.x * blockDim.x;
    for (long long r = tid; r < n; r += stride) {
        float l0 = logits[3 * r], l1 = logits[3 * r + 1], l2 = logits[3 * r + 2];
        int b = idx[r];
        atomicAdd(&sums[2 * b],     l1 + l2);
        atomicAdd(&sums[2 * b + 1], l0);
    }
}

__global__ void finalize_kernel(const float* __restrict__ sums,
                                float* __restrict__ out, int total)
{
    int j = blockIdx.x * blockDim.x + threadIdx.x;
    if (j >= total) return;
    float s = sums[j];
    float C = (j & 1) ? 5.0f : 1.0f;
    float x = KSHARP * (C - s);
    float sig;
    if (x >= 0.0f) { sig = 1.0f / (1.0f + expf(-x)); }
    else           { float e = expf(x); sig = e / (1.0f + e); }
    out[j] = logf(sig + EPS);
}

extern "C" void kernel_launch(void* const* d_in, const int* in_sizes, int n_in,
                              void* d_out, int out_size, void* d_ws, size_t ws_size,
                              hipStream_t stream) {
    const float* logits = (const float*)d_in[0];
    const int*   idx    = (const int*)d_in[1];
    int n     = in_sizes[1];       // rows (8388608)
    int batch = out_size / 2;      // 8192
    float* out = (float*)d_out;

    const size_t SLAB = (size_t)SEG * 8;          // 64 KiB
    int slabs_total = (int)(ws_size / SLAB);

    if (batch <= SEG && slabs_total >= 8) {
        // nb = 256: 1 block/CU, halves partials round-trip vs 512;
        // chunk/batch = 4 keeps packed-field overflow probability ~1e-12.
        int nb = slabs_total < 256 ? slabs_total : 256;
        long long chunk_ll = ((long long)n + nb - 1) / nb;
        int chunk = (int)((chunk_ll + 3) & ~3LL);
        if (chunk <= 8 * batch) {
            unsigned long long* partials = (unsigned long long*)d_ws;
            seg_pack_kernel<<<nb, 1024, 0, stream>>>(logits, idx, partials, n, chunk);
            dim3 rb(64, 16);
            reduce_pack_kernel<<<SEG / 128, rb, 0, stream>>>(partials, out, nb, batch);
        } else {
            // secondary: u32 path (2 LDS atomics per row), supports any chunk
            int* partials = (int*)d_ws;
            int nb2 = (int)(ws_size / ((size_t)S2 * 4));
            if (nb2 > 512) nb2 = 512;
            long long c2 = ((long long)n + nb2 - 1) / nb2;
            int chunk2 = (int)((c2 + 3) & ~3LL);
            seg_partial_kernel<<<nb2, 1024, 0, stream>>>(logits, idx, partials, n, chunk2);
            dim3 rb(64, 16);
            reduce_finalize_kernel<<<S2 / 256, rb, 0, stream>>>(partials, out, nb2, batch);
        }
    } else {
        float* sums = (float*)d_ws;
        hipMemsetAsync(sums, 0, (size_t)2 * batch * sizeof(float), stream);
        int threads = 256;
        int blocks = (n + threads - 1) / threads;
        if (blocks > 2048) blocks = 2048;
        accum_atomic_kernel<<<blocks, threads, 0, stream>>>(logits, idx, sums, n);
        int total = 2 * batch;
        finalize_kernel<<<(total + 255) / 256, 256, 0, stream>>>(sums, out, total);
    }
}